// Round 3
// baseline (2854.353 us; speedup 1.0000x reference)
//
#include <hip/hip_runtime.h>
#include <cstdint>
#include <cstddef>

#define DIM 64

typedef float f32x4 __attribute__((ext_vector_type(4)));

// ---- output element offsets (float32 elements, reference return order) ----
static constexpr size_t OFF_FH = 0;                  // fused_H   [32768][3584]
static constexpr size_t OFF_H0 = 117440512;          // H0        [32768][2048]
static constexpr size_t OFF_H1 = 184549376;          // H1        [16384][1024]
static constexpr size_t OFF_H2 = 201326592;          // H2        [8192][512]
static constexpr size_t OFF_B0 = 205520896;          // bins0
static constexpr size_t OFF_B1 = 272629760;          // bins1
static constexpr size_t OFF_B2 = 289406976;          // bins2
static constexpr size_t OFF_FB = 293601280;          // fused_bin [32768][3584]
static constexpr size_t OFF_R0 = 411041792;          // retain0 [2048]
static constexpr size_t OFF_R1 = 411043840;          // retain1 [1024]
static constexpr size_t OFF_R2 = 411044864;          // retain2 [512]
static constexpr size_t OFF_RF = 411045376;          // fused_retain [3584]

// f32-grade exp(x) as a double, x >= 0, chain-free.
__device__ __forceinline__ double exp2split(float x) {
  const float f = x * 1.44269504f;
  const int i = (int)f;              // trunc; f >= 0
  const float r = f - (float)i;
  const float e = exp2f(r);
  const unsigned long long sc = (unsigned long long)(1023 + i) << 52;
  return (double)e * __longlong_as_double((long long)sc);
}

__global__ void k_init(float* __restrict__ out, unsigned int* __restrict__ wsMM,
                       unsigned long long* __restrict__ wsBlend,
                       unsigned int* __restrict__ fixCnt) {
  const int t = threadIdx.x;
  for (int i = t; i < 7168; i += 256) out[OFF_R0 + i] = 0.0f;
  if (t < 3) {
    wsMM[2 * t + 0] = 0x7F7FFFFFu;  // FLT_MAX bits (init min)
    wsMM[2 * t + 1] = 0u;           // init max (all > 0)
    wsBlend[t] = 0ull;              // blend max (positive doubles)
  }
  if (t == 0) *fixCnt = 0u;
}

// kmm_lite: exact init min/max reading only the structurally non-uniform rows.
__global__ __launch_bounds__(256) void kmm_lite(
    const float* __restrict__ init0, const float* __restrict__ init1,
    const float* __restrict__ init2, unsigned int* __restrict__ wsMM) {
  __shared__ float sMin[3][4], sMax[3][4];
  const int t = threadIdx.x;
  const int lane = t & 63;
  const int wave = t >> 6;
  const int gid = blockIdx.x * 256 + t;
  const int stride = gridDim.x * 256;
  const float* inits[3] = {init0, init1, init2};
  const int h4v[3] = {512, 256, 128};                       // h/4
  const long bandStart[3] = {15704064L, 3919872L, 976896L}; // (n-h-K-32)*h/4
  const int bandCnt[3] = {1073152, 274432, 71680};          // bandRows*h/4
#pragma unroll
  for (int lv = 0; lv < 3; ++lv) {
    float mn = __uint_as_float(0x7F7FFFFFu), mx = 0.0f;
    const float4* p = (const float4*)inits[lv];
    const int tot = bandCnt[lv] + h4v[lv];
    for (int i = gid; i < tot; i += stride) {
      const long idx = (i < h4v[lv]) ? (long)i : bandStart[lv] + (long)(i - h4v[lv]);
      const float4 v = p[idx];
      mn = fminf(mn, fminf(fminf(v.x, v.y), fminf(v.z, v.w)));
      mx = fmaxf(mx, fmaxf(fmaxf(v.x, v.y), fmaxf(v.z, v.w)));
    }
#pragma unroll
    for (int d = 1; d < 64; d <<= 1) {
      mn = fminf(mn, __shfl_xor(mn, d));
      mx = fmaxf(mx, __shfl_xor(mx, d));
    }
    if (lane == 0) { sMin[lv][wave] = mn; sMax[lv][wave] = mx; }
  }
  __syncthreads();
  if (t < 3) {
    const float a = fminf(fminf(sMin[t][0], sMin[t][1]), fminf(sMin[t][2], sMin[t][3]));
    const float b = fmaxf(fmaxf(sMax[t][0], sMax[t][1]), fmaxf(sMax[t][2], sMax[t][3]));
    atomicMin(wsMM + 2 * t + 0, __float_as_uint(a));
    atomicMax(wsMM + 2 * t + 1, __float_as_uint(b));
  }
}

// k1a v2: GEMM (R5 core unchanged) + fused epilogue. NO xt write.
// Per chunk: per-thread f64 exp-sum registers ps[8] (thread owns the same 8
// rows for all chunks) + candidate push (hv >= T0) into compact per-row
// global buffers (LDS counters; rows exclusive to this block).
// Validity 16 <= cnt <= 128 checked in k1b; rare failures -> k1fix.
__global__ __launch_bounds__(256, 2) void k1a(
    const float* __restrict__ node0, const float* __restrict__ node1, const float* __restrict__ node2,
    const float* __restrict__ edge0, const float* __restrict__ edge1, const float* __restrict__ edge2,
    unsigned long long* __restrict__ gC0, unsigned long long* __restrict__ gC1, unsigned long long* __restrict__ gC2,
    unsigned int* __restrict__ cnt0, unsigned int* __restrict__ cnt1, unsigned int* __restrict__ cnt2,
    double* __restrict__ rs0, double* __restrict__ rs1, double* __restrict__ rs2) {
  __shared__ float sA[64 * 132];
  __shared__ float sB[64 * 132];
  __shared__ unsigned int pCnt[128];

  const int b = blockIdx.x;
  int bloc, E;
  const float *node, *edge;
  unsigned long long* gC;
  unsigned int* cnt;
  double* rs;
  float T0;
  if (b < 256)      { bloc = b;       node = node0; edge = edge0; E = 2048; gC = gC0; cnt = cnt0; rs = rs0; T0 = 45.0f; }
  else if (b < 384) { bloc = b - 256; node = node1; edge = edge1; E = 1024; gC = gC1; cnt = cnt1; rs = rs1; T0 = 35.0f; }
  else              { bloc = b - 384; node = node2; edge = edge2; E = 512;  gC = gC2; cnt = cnt2; rs = rs2; T0 = 30.0f; }

  const int t = threadIdx.x;
  const int row0 = bloc * 128;
  const int tr8 = (t >> 4) << 3;
  const int tc8 = (t & 15) << 3;

  if (t < 128) pCnt[t] = 0u;

  double ps[8];
#pragma unroll
  for (int i = 0; i < 8; ++i) ps[i] = 0.0;

  for (int c0 = 0; c0 < E; c0 += 128) {
    __syncthreads();
#pragma unroll
    for (int p = 0; p < 8; ++p) {
      const int idx = t + (p << 8);
      const int kc = (idx >> 7) << 2;
      const int r = idx & 127;
      const float4 v = *(const float4*)(node + (size_t)(row0 + r) * DIM + kc);
      sA[(kc + 0) * 132 + r] = v.x; sA[(kc + 1) * 132 + r] = v.y;
      sA[(kc + 2) * 132 + r] = v.z; sA[(kc + 3) * 132 + r] = v.w;
      const float4 w = *(const float4*)(edge + (size_t)(c0 + r) * DIM + kc);
      sB[(kc + 0) * 132 + r] = w.x; sB[(kc + 1) * 132 + r] = w.y;
      sB[(kc + 2) * 132 + r] = w.z; sB[(kc + 3) * 132 + r] = w.w;
    }
    __syncthreads();

    float acc[8][8];
#pragma unroll
    for (int i = 0; i < 8; ++i)
#pragma unroll
      for (int j = 0; j < 8; ++j) acc[i][j] = 0.0f;

#pragma unroll 2
    for (int k = 0; k < 64; ++k) {
      const float4 a0 = *(const float4*)&sA[k * 132 + tr8];
      const float4 a1 = *(const float4*)&sA[k * 132 + tr8 + 4];
      const float4 b0 = *(const float4*)&sB[k * 132 + tc8];
      const float4 b1 = *(const float4*)&sB[k * 132 + tc8 + 4];
      const float av[8] = {a0.x, a0.y, a0.z, a0.w, a1.x, a1.y, a1.z, a1.w};
      const float bv[8] = {b0.x, b0.y, b0.z, b0.w, b1.x, b1.y, b1.z, b1.w};
#pragma unroll
      for (int i = 0; i < 8; ++i)
#pragma unroll
        for (int j = 0; j < 8; ++j) acc[i][j] = fmaf(av[i], bv[j], acc[i][j]);
    }

    // ---- fused epilogue: exp-sum (f64 regs) + candidate push ----
#pragma unroll
    for (int i = 0; i < 8; ++i) {
      const int rloc = tr8 + i;
#pragma unroll
      for (int j = 0; j < 8; ++j) {
        const float hv = fmaxf(3.0f * acc[i][j], 0.0f);
        ps[i] += exp2split(hv);
        if (hv >= T0) {
          const unsigned int sl = atomicAdd(&pCnt[rloc], 1u);
          if (sl < 128u) {
            const unsigned int col = (unsigned int)(c0 + tc8 + j);
            gC[((size_t)(row0 + rloc) << 7) + sl] =
                ((unsigned long long)__float_as_uint(hv) << 32) |
                (unsigned long long)(0xFFFFFFFFu - col);
          }
        }
      }
    }
  }

  // per-row exp-sum: reduce across the 16 threads (consecutive lanes) sharing rows
#pragma unroll
  for (int i = 0; i < 8; ++i) {
    double v = ps[i];
    v += __shfl_xor(v, 1);
    v += __shfl_xor(v, 2);
    v += __shfl_xor(v, 4);
    v += __shfl_xor(v, 8);
    ps[i] = v;
  }
  if ((t & 15) == 0) {
#pragma unroll
    for (int i = 0; i < 8; ++i) rs[row0 + tr8 + i] = ps[i];
  }
  __syncthreads();
  if (t < 128) cnt[row0 + t] = pCnt[t];
}

// k1b v4: wave per row, NO bulk xt read. Loads <=128 candidates + rowSum,
// validates 16<=cnt<=128 (=> candidates superset of top-16), tournament
// top-16, f64 head fix + blend (proven tail). Invalid rows -> fix list.
__global__ __launch_bounds__(256) void k1b(
    const float* __restrict__ node0, const float* __restrict__ node1, const float* __restrict__ node2,
    const float* __restrict__ edge0, const float* __restrict__ edge1, const float* __restrict__ edge2,
    const float* __restrict__ init0, const float* __restrict__ init1, const float* __restrict__ init2,
    const unsigned long long* __restrict__ gC0, const unsigned long long* __restrict__ gC1, const unsigned long long* __restrict__ gC2,
    const unsigned int* __restrict__ cnt0, const unsigned int* __restrict__ cnt1, const unsigned int* __restrict__ cnt2,
    const double* __restrict__ rs0, const double* __restrict__ rs1, const double* __restrict__ rs2,
    int* __restrict__ tIdx0, int* __restrict__ tIdx1, int* __restrict__ tIdx2,
    double* __restrict__ tCur0, double* __restrict__ tCur1, double* __restrict__ tCur2,
    unsigned long long* __restrict__ wsBlend,
    unsigned int* __restrict__ fixCnt, unsigned int* __restrict__ fixRows) {
  const int t = threadIdx.x;
  const int lane = t & 63;
  const int wave = t >> 6;
  const int gw = blockIdx.x * 4 + wave;
  int lvl, row, E;
  const float *node, *edge, *init;
  const unsigned long long* gC;
  const unsigned int* cnt;
  const double* rs;
  int* tIdx;
  double* tCur;
  if (gw < 32768)      { lvl = 0; row = gw;          E = 2048; node = node0; edge = edge0; init = init0; gC = gC0; cnt = cnt0; rs = rs0; tIdx = tIdx0; tCur = tCur0; }
  else if (gw < 49152) { lvl = 1; row = gw - 32768;  E = 1024; node = node1; edge = edge1; init = init1; gC = gC1; cnt = cnt1; rs = rs1; tIdx = tIdx1; tCur = tCur1; }
  else                 { lvl = 2; row = gw - 49152;  E = 512;  node = node2; edge = edge2; init = init2; gC = gC2; cnt = cnt2; rs = rs2; tIdx = tIdx2; tCur = tCur2; }

  const unsigned int c = cnt[row];
  if (c < 16u || c > 128u) {  // threshold failed for this row -> exact fixup
    if (lane == 0) {
      const unsigned int p = atomicAdd(fixCnt, 1u);
      fixRows[p] = ((unsigned int)lvl << 28) | (unsigned int)row;
    }
    return;  // wave-uniform
  }

  const unsigned long long* gr = gC + ((size_t)row << 7);
  unsigned long long c0 = (lane < (int)c) ? gr[lane] : 0ull;
  unsigned long long c1 = (64 + lane < (int)c) ? gr[64 + lane] : 0ull;
  unsigned long long mywin = 0ull;
#pragma unroll 1
  for (int round = 0; round < 16; ++round) {
    unsigned long long lm = (c0 > c1) ? c0 : c1;
#pragma unroll
    for (int d = 1; d < 64; d <<= 1) {
      const unsigned long long o = __shfl_xor(lm, d);
      lm = (o > lm) ? o : lm;
    }
    if (c0 == lm) c0 = 0ull; else if (c1 == lm) c1 = 0ull;
    if (lane == round) mywin = lm;
  }

  const double sAll = rs[row];

  // ---- f64 head recompute on lanes 0..15 (proven tail) ----
  double eh = 0.0, h32 = 0.0;
  int gc = 0;
  if (lane < 16) {
    const float x32 = __uint_as_float((unsigned int)(mywin >> 32));
    const unsigned int gcr = 0xFFFFFFFFu - (unsigned int)(mywin & 0xFFFFFFFFull);
    gc = (int)min(gcr, (unsigned int)(E - 1));  // OOB insurance (degenerate only)
    const float4* n4 = (const float4*)(node + (size_t)row * DIM);
    const float4* e4 = (const float4*)(edge + (size_t)gc * DIM);
    double acc = 0.0;
#pragma unroll
    for (int j = 0; j < 16; ++j) {
      const float4 a = n4[j], bb = e4[j];
      acc += (double)a.x * (double)bb.x + (double)a.y * (double)bb.y +
             (double)a.z * (double)bb.z + (double)a.w * (double)bb.w;
    }
    eh = exp(fmax(3.0 * acc, 0.0));
    h32 = exp2split(x32);
  }
  double ehsum = eh, h32sum = h32;
#pragma unroll
  for (int d = 1; d < 64; d <<= 1) {
    ehsum += __shfl_xor(ehsum, d);
    h32sum += __shfl_xor(h32sum, d);
  }
  const double sFix = fmax(sAll - h32sum, 0.0) + ehsum;

  double blend = 0.0;
  if (lane < 16) {
    const double cur = eh / sFix;
    tIdx[(size_t)row * 16 + lane] = gc;
    tCur[(size_t)row * 16 + lane] = cur;
    blend = 0.5 * ((double)init[(size_t)row * E + gc] + cur);
  }
#pragma unroll
  for (int d = 1; d < 64; d <<= 1) {
    const double o = __shfl_xor(blend, d);
    blend = fmax(blend, o);
  }
  if (lane == 0)
    atomicMax(wsBlend + lvl, (unsigned long long)__double_as_longlong(blend));
}

// k1fix: exact per-row fallback (expected 0 rows). Wave per flagged row:
// recompute the full xt row from node/edge (L2-hot), then the proven
// old-k1b path: lane-max threshold, LDS compaction, tournament, f64 head.
__global__ __launch_bounds__(256) void k1fix(
    const float* __restrict__ node0, const float* __restrict__ node1, const float* __restrict__ node2,
    const float* __restrict__ edge0, const float* __restrict__ edge1, const float* __restrict__ edge2,
    const float* __restrict__ init0, const float* __restrict__ init1, const float* __restrict__ init2,
    int* __restrict__ tIdx0, int* __restrict__ tIdx1, int* __restrict__ tIdx2,
    double* __restrict__ tCur0, double* __restrict__ tCur1, double* __restrict__ tCur2,
    unsigned long long* __restrict__ wsBlend,
    const unsigned int* __restrict__ fixCnt, const unsigned int* __restrict__ fixRows) {
  __shared__ unsigned long long cands[4][136];
  __shared__ int cnt4[4];
  const int t = threadIdx.x;
  const int lane = t & 63;
  const int wave = t >> 6;
  const unsigned int nF = *fixCnt;
  for (unsigned int f = (unsigned int)(blockIdx.x * 4 + wave); f < nF; f += 256u) {
    const unsigned int rec = fixRows[f];
    const int lvl = (int)(rec >> 28);
    const int row = (int)(rec & 0x0FFFFFFFu);
    const float *node, *edge, *init;
    int E; int* tIdx; double* tCur;
    if (lvl == 0)      { node = node0; edge = edge0; init = init0; E = 2048; tIdx = tIdx0; tCur = tCur0; }
    else if (lvl == 1) { node = node1; edge = edge1; init = init1; E = 1024; tIdx = tIdx1; tCur = tCur1; }
    else               { node = node2; edge = edge2; init = init2; E = 512;  tIdx = tIdx2; tCur = tCur2; }

    float4 nreg[16];
    const float4* nrow = (const float4*)(node + (size_t)row * DIM);
#pragma unroll
    for (int k = 0; k < 16; ++k) nreg[k] = nrow[k];

    const int nC = E >> 6;  // cols per lane
    float vals[32];
    float lmax = 0.0f;
    double s = 0.0;
#pragma unroll
    for (int j = 0; j < 32; ++j) {
      if (j < nC) {
        const int col = lane + (j << 6);
        const float4* e4 = (const float4*)(edge + (size_t)col * DIM);
        float a = 0.0f;
#pragma unroll
        for (int k = 0; k < 16; ++k) {
          const float4 ev = e4[k];
          a = fmaf(nreg[k].x, ev.x, a);
          a = fmaf(nreg[k].y, ev.y, a);
          a = fmaf(nreg[k].z, ev.z, a);
          a = fmaf(nreg[k].w, ev.w, a);
        }
        const float hv = fmaxf(3.0f * a, 0.0f);
        vals[j] = hv;
        s += exp2split(hv);
        lmax = fmaxf(lmax, hv);
      }
    }

    if (lane == 0) cnt4[wave] = 0;
    float curm = lmax, T = 0.0f;
#pragma unroll 1
    for (int round = 0; round < 16; ++round) {
      float wm = curm;
#pragma unroll
      for (int d = 1; d < 64; d <<= 1) wm = fmaxf(wm, __shfl_xor(wm, d));
      T = wm;
      curm = (curm == wm) ? -1.0f : curm;
    }
    T = fmaxf(T, 1e-37f);

#pragma unroll
    for (int j = 0; j < 32; ++j) {
      if (j < nC && vals[j] >= T) {
        const int sl = atomicAdd(&cnt4[wave], 1);
        if (sl < 128) {
          cands[wave][sl] =
              ((unsigned long long)__float_as_uint(vals[j]) << 32) |
              (unsigned long long)(0xFFFFFFFFu - (unsigned int)(lane + (j << 6)));
        }
      }
    }

    const int count = min(cnt4[wave], 128);
    unsigned long long c0 = (lane < count) ? cands[wave][lane] : 0ull;
    unsigned long long c1 = (64 + lane < count) ? cands[wave][64 + lane] : 0ull;
    unsigned long long mywin = 0ull;
#pragma unroll 1
    for (int round = 0; round < 16; ++round) {
      unsigned long long lm = (c0 > c1) ? c0 : c1;
#pragma unroll
      for (int d = 1; d < 64; d <<= 1) {
        const unsigned long long o = __shfl_xor(lm, d);
        lm = (o > lm) ? o : lm;
      }
      if (c0 == lm) c0 = 0ull; else if (c1 == lm) c1 = 0ull;
      if (lane == round) mywin = lm;
    }

    double sAll = s;
#pragma unroll
    for (int d = 1; d < 64; d <<= 1) sAll += __shfl_xor(sAll, d);

    double eh = 0.0, h32 = 0.0;
    int gc = 0;
    if (lane < 16) {
      const float x32 = __uint_as_float((unsigned int)(mywin >> 32));
      const unsigned int gcr = 0xFFFFFFFFu - (unsigned int)(mywin & 0xFFFFFFFFull);
      gc = (int)min(gcr, (unsigned int)(E - 1));
      const float4* e4 = (const float4*)(edge + (size_t)gc * DIM);
      double acc = 0.0;
#pragma unroll
      for (int j = 0; j < 16; ++j) {
        const float4 a = nreg[j], bb = e4[j];
        acc += (double)a.x * (double)bb.x + (double)a.y * (double)bb.y +
               (double)a.z * (double)bb.z + (double)a.w * (double)bb.w;
      }
      eh = exp(fmax(3.0 * acc, 0.0));
      h32 = exp2split(x32);
    }
    double ehsum = eh, h32sum = h32;
#pragma unroll
    for (int d = 1; d < 64; d <<= 1) {
      ehsum += __shfl_xor(ehsum, d);
      h32sum += __shfl_xor(h32sum, d);
    }
    const double sFixv = fmax(sAll - h32sum, 0.0) + ehsum;

    double blend = 0.0;
    if (lane < 16) {
      const double cur = eh / sFixv;
      tIdx[(size_t)row * 16 + lane] = gc;
      tCur[(size_t)row * 16 + lane] = cur;
      blend = 0.5 * ((double)init[(size_t)row * E + gc] + cur);
    }
#pragma unroll
    for (int d = 1; d < 64; d <<= 1) {
      const double o = __shfl_xor(blend, d);
      blend = fmax(blend, o);
    }
    if (lane == 0)
      atomicMax(wsBlend + lvl, (unsigned long long)__double_as_longlong(blend));
  }
}

// Analytic init band parameters (verified R7).
__device__ __forceinline__ void bandParams(int i, int n, int h, int& lo, int& hi,
                                           float& vOn, float& vOff) {
  const float EINV = 0.36787944117144233f;
  const int hiRaw = i - (n - h - 17);
  if (hiRaw < 0) {
    lo = 1; hi = 0;
    vOff = 1.0f / (float)h;
    vOn = vOff;
  } else {
    lo = max(0, i - (n - h));
    hi = min(h - 1, hiRaw);
    const float m = (float)(hi - lo + 1);
    const float sum = m + ((float)h - m) * EINV;
    vOn = 1.0f / sum;
    vOff = EINV / sum;
  }
}

// Shared row-build: analytic base + 48 f64 top-k fixes into fH/fB.
__device__ __forceinline__ void buildRow(
    int r, int t, float* fH, float* fB,
    const float* init0, const float* init1, const float* init2,
    const int* tIdx0, const int* tIdx1, const int* tIdx2,
    const double* tCur0, const double* tCur1, const double* tCur2,
    const unsigned int* wsMM, const unsigned long long* wsBlend,
    float* out, bool doRetain) {
  const int r1 = r >> 1, r2 = r >> 2;
  const double mn0 = 0.5 * (double)__uint_as_float(wsMM[0]);
  const double mx0 = fmax(0.5 * (double)__uint_as_float(wsMM[1]),
                          __longlong_as_double((long long)wsBlend[0]));
  const double inv0 = 1.0 / (mx0 - mn0);
  const double mn1 = 0.5 * (double)__uint_as_float(wsMM[2]);
  const double mx1 = fmax(0.5 * (double)__uint_as_float(wsMM[3]),
                          __longlong_as_double((long long)wsBlend[1]));
  const double inv1 = 1.0 / (mx1 - mn1);
  const double mn2 = 0.5 * (double)__uint_as_float(wsMM[4]);
  const double mx2 = fmax(0.5 * (double)__uint_as_float(wsMM[5]),
                          __longlong_as_double((long long)wsBlend[2]));
  const double inv2 = 1.0 / (mx2 - mn2);

  {  // level0 cols [0,2048)
    int lo, hi; float vOn, vOff;
    bandParams(r, 32768, 2048, lo, hi, vOn, vOff);
    const float mnl = (float)mn0, il = (float)inv0;
    const float hOn = (0.5f * vOn - mnl) * il, hOff = (0.5f * vOff - mnl) * il;
#pragma unroll
    for (int p = 0; p < 2; ++p) {
      const int c = (t + (p << 8)) << 2;
      float4 h, bb;
      h.x = (c + 0 >= lo && c + 0 <= hi) ? hOn : hOff;
      h.y = (c + 1 >= lo && c + 1 <= hi) ? hOn : hOff;
      h.z = (c + 2 >= lo && c + 2 <= hi) ? hOn : hOff;
      h.w = (c + 3 >= lo && c + 3 <= hi) ? hOn : hOff;
      bb.x = (h.x > 0.5f) ? 1.0f : 0.0f; bb.y = (h.y > 0.5f) ? 1.0f : 0.0f;
      bb.z = (h.z > 0.5f) ? 1.0f : 0.0f; bb.w = (h.w > 0.5f) ? 1.0f : 0.0f;
      *(float4*)&fH[c] = h; *(float4*)&fB[c] = bb;
      if (doRetain && bb.x + bb.y + bb.z + bb.w > 0.0f) {
        if (bb.x > 0.0f) { out[OFF_R0 + c + 0] = 1.0f; out[OFF_RF + c + 0] = 1.0f; }
        if (bb.y > 0.0f) { out[OFF_R0 + c + 1] = 1.0f; out[OFF_RF + c + 1] = 1.0f; }
        if (bb.z > 0.0f) { out[OFF_R0 + c + 2] = 1.0f; out[OFF_RF + c + 2] = 1.0f; }
        if (bb.w > 0.0f) { out[OFF_R0 + c + 3] = 1.0f; out[OFF_RF + c + 3] = 1.0f; }
      }
    }
  }
  {  // level1 cols [2048,3072)
    int lo, hi; float vOn, vOff;
    bandParams(r1, 16384, 1024, lo, hi, vOn, vOff);
    const float mnl = (float)mn1, il = (float)inv1;
    const float hOn = (0.5f * vOn - mnl) * il, hOff = (0.5f * vOff - mnl) * il;
    const int cl = t << 2;
    const int c = 2048 + cl;
    float4 h, bb;
    h.x = (cl + 0 >= lo && cl + 0 <= hi) ? hOn : hOff;
    h.y = (cl + 1 >= lo && cl + 1 <= hi) ? hOn : hOff;
    h.z = (cl + 2 >= lo && cl + 2 <= hi) ? hOn : hOff;
    h.w = (cl + 3 >= lo && cl + 3 <= hi) ? hOn : hOff;
    bb.x = (h.x > 0.5f) ? 1.0f : 0.0f; bb.y = (h.y > 0.5f) ? 1.0f : 0.0f;
    bb.z = (h.z > 0.5f) ? 1.0f : 0.0f; bb.w = (h.w > 0.5f) ? 1.0f : 0.0f;
    *(float4*)&fH[c] = h; *(float4*)&fB[c] = bb;
    if (doRetain && bb.x + bb.y + bb.z + bb.w > 0.0f) {
      if (bb.x > 0.0f) { out[OFF_R1 + cl + 0] = 1.0f; out[OFF_RF + c + 0] = 1.0f; }
      if (bb.y > 0.0f) { out[OFF_R1 + cl + 1] = 1.0f; out[OFF_RF + c + 1] = 1.0f; }
      if (bb.z > 0.0f) { out[OFF_R1 + cl + 2] = 1.0f; out[OFF_RF + c + 2] = 1.0f; }
      if (bb.w > 0.0f) { out[OFF_R1 + cl + 3] = 1.0f; out[OFF_RF + c + 3] = 1.0f; }
    }
  }
  if (t < 128) {  // level2 cols [3072,3584)
    int lo, hi; float vOn, vOff;
    bandParams(r2, 8192, 512, lo, hi, vOn, vOff);
    const float mnl = (float)mn2, il = (float)inv2;
    const float hOn = (0.5f * vOn - mnl) * il, hOff = (0.5f * vOff - mnl) * il;
    const int cl = t << 2;
    const int c = 3072 + cl;
    float4 h, bb;
    h.x = (cl + 0 >= lo && cl + 0 <= hi) ? hOn : hOff;
    h.y = (cl + 1 >= lo && cl + 1 <= hi) ? hOn : hOff;
    h.z = (cl + 2 >= lo && cl + 2 <= hi) ? hOn : hOff;
    h.w = (cl + 3 >= lo && cl + 3 <= hi) ? hOn : hOff;
    bb.x = (h.x > 0.5f) ? 1.0f : 0.0f; bb.y = (h.y > 0.5f) ? 1.0f : 0.0f;
    bb.z = (h.z > 0.5f) ? 1.0f : 0.0f; bb.w = (h.w > 0.5f) ? 1.0f : 0.0f;
    *(float4*)&fH[c] = h; *(float4*)&fB[c] = bb;
    if (doRetain && bb.x + bb.y + bb.z + bb.w > 0.0f) {
      if (bb.x > 0.0f) { out[OFF_R2 + cl + 0] = 1.0f; out[OFF_RF + c + 0] = 1.0f; }
      if (bb.y > 0.0f) { out[OFF_R2 + cl + 1] = 1.0f; out[OFF_RF + c + 1] = 1.0f; }
      if (bb.z > 0.0f) { out[OFF_R2 + cl + 2] = 1.0f; out[OFF_RF + c + 2] = 1.0f; }
      if (bb.w > 0.0f) { out[OFF_R2 + cl + 3] = 1.0f; out[OFF_RF + c + 3] = 1.0f; }
    }
  }
  __syncthreads();

  if (t < 48) {
    const int lv = t >> 4, j = t & 15;
    int rowl, El, off;
    const int* ti; const double* tc; const float* in;
    size_t offR;
    double mnl, il;
    if (lv == 0)      { rowl = r;  El = 2048; off = 0;    ti = tIdx0; tc = tCur0; in = init0; offR = OFF_R0; mnl = mn0; il = inv0; }
    else if (lv == 1) { rowl = r1; El = 1024; off = 2048; ti = tIdx1; tc = tCur1; in = init1; offR = OFF_R1; mnl = mn1; il = inv1; }
    else              { rowl = r2; El = 512;  off = 3072; ti = tIdx2; tc = tCur2; in = init2; offR = OFF_R2; mnl = mn2; il = inv2; }
    const int gc = ti[(size_t)rowl * 16 + j];
    const double cur = tc[(size_t)rowl * 16 + j];
    const double adj = 0.5 * ((double)in[(size_t)rowl * El + gc] + cur);
    const double H = (adj - mnl) * il;
    const float hf = (float)H;
    const float bf = (H > 0.5) ? 1.0f : 0.0f;
    fH[off + gc] = hf;
    fB[off + gc] = bf;
    if (doRetain && bf > 0.0f) {
      out[offR + gc] = 1.0f;
      out[OFF_RF + off + gc] = 1.0f;
    }
  }
  __syncthreads();
}

// k2: build row ONCE, stream fused FH/FB (1.08 GB) AND per-level H/B +
// retains (0.57 GB).
__global__ __launch_bounds__(256) void k2(
    const float* __restrict__ init0, const float* __restrict__ init1, const float* __restrict__ init2,
    const int* __restrict__ tIdx0, const int* __restrict__ tIdx1, const int* __restrict__ tIdx2,
    const double* __restrict__ tCur0, const double* __restrict__ tCur1, const double* __restrict__ tCur2,
    const unsigned int* __restrict__ wsMM, const unsigned long long* __restrict__ wsBlend,
    float* __restrict__ out) {
  __shared__ float fH[3584];
  __shared__ float fB[3584];
  const int r = blockIdx.x;
  const int t = threadIdx.x;
  const int r1 = r >> 1, r2 = r >> 2;
  buildRow(r, t, fH, fB, init0, init1, init2, tIdx0, tIdx1, tIdx2,
           tCur0, tCur1, tCur2, wsMM, wsBlend, out, true);
  const f32x4* sH = (const f32x4*)fH;
  const f32x4* sB = (const f32x4*)fB;
  // fused streams
  f32x4* FH = (f32x4*)(out + OFF_FH + (size_t)r * 3584);
  f32x4* FB = (f32x4*)(out + OFF_FB + (size_t)r * 3584);
  for (int i = t; i < 896; i += 256) {
    __builtin_nontemporal_store(sH[i], &FH[i]);
    __builtin_nontemporal_store(sB[i], &FB[i]);
  }
  // per-level streams
  f32x4* H0 = (f32x4*)(out + OFF_H0 + (size_t)r * 2048);
  f32x4* B0 = (f32x4*)(out + OFF_B0 + (size_t)r * 2048);
  for (int i = t; i < 512; i += 256) {
    __builtin_nontemporal_store(sH[i], &H0[i]);
    __builtin_nontemporal_store(sB[i], &B0[i]);
  }
  if ((r & 1) == 0) {
    f32x4* H1 = (f32x4*)(out + OFF_H1 + (size_t)r1 * 1024);
    f32x4* B1 = (f32x4*)(out + OFF_B1 + (size_t)r1 * 1024);
    __builtin_nontemporal_store(sH[512 + t], &H1[t]);
    __builtin_nontemporal_store(sB[512 + t], &B1[t]);
  }
  if ((r & 3) == 0 && t < 128) {
    f32x4* H2 = (f32x4*)(out + OFF_H2 + (size_t)r2 * 512);
    f32x4* B2 = (f32x4*)(out + OFF_B2 + (size_t)r2 * 512);
    __builtin_nontemporal_store(sH[768 + t], &H2[t]);
    __builtin_nontemporal_store(sB[768 + t], &B2[t]);
  }
}

extern "C" void kernel_launch(void* const* d_in, const int* in_sizes, int n_in,
                              void* d_out, int out_size, void* d_ws, size_t ws_size,
                              hipStream_t stream) {
  (void)in_sizes; (void)n_in; (void)out_size; (void)ws_size;
  const float* node0 = (const float*)d_in[0];
  const float* node1 = (const float*)d_in[1];
  const float* node2 = (const float*)d_in[2];
  const float* edge0 = (const float*)d_in[3];
  const float* edge1 = (const float*)d_in[4];
  const float* edge2 = (const float*)d_in[5];
  const float* init0 = (const float*)d_in[6];
  const float* init1 = (const float*)d_in[7];
  const float* init2 = (const float*)d_in[8];
  float* out = (float*)d_out;

  unsigned char* ws = (unsigned char*)d_ws;
  unsigned int* wsMM = (unsigned int*)ws;                        // 6 u32 @ 0
  unsigned long long* wsBlend = (unsigned long long*)(ws + 32);  // 3 u64 @ 32
  unsigned int* fixCnt = (unsigned int*)(ws + 64);               // 1 u32 @ 64
  unsigned int* fixRows = (unsigned int*)(ws + 1024);            // 57344 u32
  int*    tIdx0 = (int*)(ws + (size_t)(1 << 20));
  int*    tIdx1 = (int*)(ws + (size_t)(3 << 20));
  int*    tIdx2 = (int*)(ws + (size_t)(4 << 20));
  double* tCur0 = (double*)(ws + (size_t)(5 << 20));
  double* tCur1 = (double*)(ws + (size_t)(9 << 20));
  double* tCur2 = (double*)(ws + (size_t)(11 << 20));
  double* rs0   = (double*)(ws + (size_t)(16 << 20));            // 32768 f64
  double* rs1   = rs0 + 32768;                                   // 16384 f64
  double* rs2   = rs1 + 16384;                                   // 8192 f64
  unsigned int* cnt0 = (unsigned int*)(ws + (size_t)(17 << 20)); // 32768 u32
  unsigned int* cnt1 = cnt0 + 32768;
  unsigned int* cnt2 = cnt1 + 16384;
  unsigned long long* gC0 = (unsigned long long*)(ws + (size_t)(20 << 20)); // 32768*128 u64
  unsigned long long* gC1 = gC0 + (size_t)32768 * 128;           // 16384*128 u64
  unsigned long long* gC2 = gC1 + (size_t)16384 * 128;           // 8192*128 u64

  k_init<<<1, 256, 0, stream>>>(out, wsMM, wsBlend, fixCnt);
  kmm_lite<<<256, 256, 0, stream>>>(init0, init1, init2, wsMM);
  k1a<<<448, 256, 0, stream>>>(node0, node1, node2, edge0, edge1, edge2,
                               gC0, gC1, gC2, cnt0, cnt1, cnt2, rs0, rs1, rs2);
  k1b<<<14336, 256, 0, stream>>>(node0, node1, node2, edge0, edge1, edge2,
                                 init0, init1, init2,
                                 gC0, gC1, gC2, cnt0, cnt1, cnt2, rs0, rs1, rs2,
                                 tIdx0, tIdx1, tIdx2, tCur0, tCur1, tCur2,
                                 wsBlend, fixCnt, fixRows);
  k1fix<<<64, 256, 0, stream>>>(node0, node1, node2, edge0, edge1, edge2,
                                init0, init1, init2,
                                tIdx0, tIdx1, tIdx2, tCur0, tCur1, tCur2,
                                wsBlend, fixCnt, fixRows);
  k2<<<32768, 256, 0, stream>>>(init0, init1, init2, tIdx0, tIdx1, tIdx2,
                                tCur0, tCur1, tCur2, wsMM, wsBlend, out);
}

// Round 6
// 2241.871 us; speedup vs baseline: 1.2732x; 1.2732x over previous
//
#include <hip/hip_runtime.h>
#include <cstdint>
#include <cstddef>

#define DIM 64

typedef float f32x4 __attribute__((ext_vector_type(4)));

// ---- output element offsets (float32 elements, reference return order) ----
static constexpr size_t OFF_FH = 0;                  // fused_H   [32768][3584]
static constexpr size_t OFF_H0 = 117440512;          // H0        [32768][2048]
static constexpr size_t OFF_H1 = 184549376;          // H1        [16384][1024]
static constexpr size_t OFF_H2 = 201326592;          // H2        [8192][512]
static constexpr size_t OFF_B0 = 205520896;          // bins0
static constexpr size_t OFF_B1 = 272629760;          // bins1
static constexpr size_t OFF_B2 = 289406976;          // bins2
static constexpr size_t OFF_FB = 293601280;          // fused_bin [32768][3584]
static constexpr size_t OFF_R0 = 411041792;          // retain0 [2048]
static constexpr size_t OFF_R1 = 411043840;          // retain1 [1024]
static constexpr size_t OFF_R2 = 411044864;          // retain2 [512]
static constexpr size_t OFF_RF = 411045376;          // fused_retain [3584]

// f32-grade exp(x) as a double, x >= 0, chain-free.
__device__ __forceinline__ double exp2split(float x) {
  const float f = x * 1.44269504f;
  const int i = (int)f;              // trunc; f >= 0
  const float r = f - (float)i;
  const float e = exp2f(r);
  const unsigned long long sc = (unsigned long long)(1023 + i) << 52;
  return (double)e * __longlong_as_double((long long)sc);
}

__global__ void k_init(float* __restrict__ out, unsigned int* __restrict__ wsMM,
                       unsigned long long* __restrict__ wsBlend) {
  const int t = threadIdx.x;
  for (int i = t; i < 7168; i += 256) out[OFF_R0 + i] = 0.0f;
  if (t < 3) {
    wsMM[2 * t + 0] = 0x7F7FFFFFu;  // FLT_MAX bits (init min)
    wsMM[2 * t + 1] = 0u;           // init max (all > 0)
    wsBlend[t] = 0ull;              // blend max (positive doubles)
  }
}

// kmm_lite: exact init min/max reading only the structurally non-uniform rows.
__global__ __launch_bounds__(256) void kmm_lite(
    const float* __restrict__ init0, const float* __restrict__ init1,
    const float* __restrict__ init2, unsigned int* __restrict__ wsMM) {
  __shared__ float sMin[3][4], sMax[3][4];
  const int t = threadIdx.x;
  const int lane = t & 63;
  const int wave = t >> 6;
  const int gid = blockIdx.x * 256 + t;
  const int stride = gridDim.x * 256;
  const float* inits[3] = {init0, init1, init2};
  const int h4v[3] = {512, 256, 128};                       // h/4
  const long bandStart[3] = {15704064L, 3919872L, 976896L}; // (n-h-K-32)*h/4
  const int bandCnt[3] = {1073152, 274432, 71680};          // bandRows*h/4
#pragma unroll
  for (int lv = 0; lv < 3; ++lv) {
    float mn = __uint_as_float(0x7F7FFFFFu), mx = 0.0f;
    const float4* p = (const float4*)inits[lv];
    const int tot = bandCnt[lv] + h4v[lv];
    for (int i = gid; i < tot; i += stride) {
      const long idx = (i < h4v[lv]) ? (long)i : bandStart[lv] + (long)(i - h4v[lv]);
      const float4 v = p[idx];
      mn = fminf(mn, fminf(fminf(v.x, v.y), fminf(v.z, v.w)));
      mx = fmaxf(mx, fmaxf(fmaxf(v.x, v.y), fmaxf(v.z, v.w)));
    }
#pragma unroll
    for (int d = 1; d < 64; d <<= 1) {
      mn = fminf(mn, __shfl_xor(mn, d));
      mx = fmaxf(mx, __shfl_xor(mx, d));
    }
    if (lane == 0) { sMin[lv][wave] = mn; sMax[lv][wave] = mx; }
  }
  __syncthreads();
  if (t < 3) {
    const float a = fminf(fminf(sMin[t][0], sMin[t][1]), fminf(sMin[t][2], sMin[t][3]));
    const float b = fmaxf(fmaxf(sMax[t][0], sMax[t][1]), fmaxf(sMax[t][2], sMax[t][3]));
    atomicMin(wsMM + 2 * t + 0, __float_as_uint(a));
    atomicMax(wsMM + 2 * t + 1, __float_as_uint(b));
  }
}

// k1a: pure GEMM (R5 verbatim). xt = relu(3a) -> ws.
__global__ __launch_bounds__(256, 2) void k1a(
    const float* __restrict__ node0, const float* __restrict__ node1, const float* __restrict__ node2,
    const float* __restrict__ edge0, const float* __restrict__ edge1, const float* __restrict__ edge2,
    float* __restrict__ xt0, float* __restrict__ xt1, float* __restrict__ xt2) {
  __shared__ float sA[64 * 132];
  __shared__ float sB[64 * 132];

  const int b = blockIdx.x;
  int bloc, E;
  const float *node, *edge;
  float* xt;
  if (b < 256)      { bloc = b;       node = node0; edge = edge0; xt = xt0; E = 2048; }
  else if (b < 384) { bloc = b - 256; node = node1; edge = edge1; xt = xt1; E = 1024; }
  else              { bloc = b - 384; node = node2; edge = edge2; xt = xt2; E = 512;  }

  const int t = threadIdx.x;
  const int row0 = bloc * 128;
  const int tr8 = (t >> 4) << 3;
  const int tc8 = (t & 15) << 3;

  for (int c0 = 0; c0 < E; c0 += 128) {
    __syncthreads();
#pragma unroll
    for (int p = 0; p < 8; ++p) {
      const int idx = t + (p << 8);
      const int kc = (idx >> 7) << 2;
      const int r = idx & 127;
      const float4 v = *(const float4*)(node + (size_t)(row0 + r) * DIM + kc);
      sA[(kc + 0) * 132 + r] = v.x; sA[(kc + 1) * 132 + r] = v.y;
      sA[(kc + 2) * 132 + r] = v.z; sA[(kc + 3) * 132 + r] = v.w;
      const float4 w = *(const float4*)(edge + (size_t)(c0 + r) * DIM + kc);
      sB[(kc + 0) * 132 + r] = w.x; sB[(kc + 1) * 132 + r] = w.y;
      sB[(kc + 2) * 132 + r] = w.z; sB[(kc + 3) * 132 + r] = w.w;
    }
    __syncthreads();

    float acc[8][8];
#pragma unroll
    for (int i = 0; i < 8; ++i)
#pragma unroll
      for (int j = 0; j < 8; ++j) acc[i][j] = 0.0f;

#pragma unroll 2
    for (int k = 0; k < 64; ++k) {
      const float4 a0 = *(const float4*)&sA[k * 132 + tr8];
      const float4 a1 = *(const float4*)&sA[k * 132 + tr8 + 4];
      const float4 b0 = *(const float4*)&sB[k * 132 + tc8];
      const float4 b1 = *(const float4*)&sB[k * 132 + tc8 + 4];
      const float av[8] = {a0.x, a0.y, a0.z, a0.w, a1.x, a1.y, a1.z, a1.w};
      const float bv[8] = {b0.x, b0.y, b0.z, b0.w, b1.x, b1.y, b1.z, b1.w};
#pragma unroll
      for (int i = 0; i < 8; ++i)
#pragma unroll
        for (int j = 0; j < 8; ++j) acc[i][j] = fmaf(av[i], bv[j], acc[i][j]);
    }

#pragma unroll
    for (int i = 0; i < 8; ++i) {
      f32x4 h0, h1;
      h0.x = fmaxf(3.0f * acc[i][0], 0.0f); h0.y = fmaxf(3.0f * acc[i][1], 0.0f);
      h0.z = fmaxf(3.0f * acc[i][2], 0.0f); h0.w = fmaxf(3.0f * acc[i][3], 0.0f);
      h1.x = fmaxf(3.0f * acc[i][4], 0.0f); h1.y = fmaxf(3.0f * acc[i][5], 0.0f);
      h1.z = fmaxf(3.0f * acc[i][6], 0.0f); h1.w = fmaxf(3.0f * acc[i][7], 0.0f);
      float* dst = xt + (size_t)(row0 + tr8 + i) * E + c0 + tc8;
      *(f32x4*)dst = h0;
      *(f32x4*)(dst + 4) = h1;
    }
  }
}

// k1b v3: one wave per row, SINGLE global pass. Row values stay register-
// resident (<=8 float4/lane); candidate compaction reads registers.
// Threshold T = 16th distinct wave max of lane maxes (provably <= x_(16) ->
// candidates superset of top-16). Then f64 head fix + blend (proven tail).
__global__ __launch_bounds__(256) void k1b(
    const float* __restrict__ node0, const float* __restrict__ node1, const float* __restrict__ node2,
    const float* __restrict__ edge0, const float* __restrict__ edge1, const float* __restrict__ edge2,
    const float* __restrict__ init0, const float* __restrict__ init1, const float* __restrict__ init2,
    const float* __restrict__ xt0, const float* __restrict__ xt1, const float* __restrict__ xt2,
    int* __restrict__ tIdx0, int* __restrict__ tIdx1, int* __restrict__ tIdx2,
    double* __restrict__ tCur0, double* __restrict__ tCur1, double* __restrict__ tCur2,
    unsigned long long* __restrict__ wsBlend) {
  __shared__ unsigned long long cands[4][136];
  __shared__ int cnt[4];
  __shared__ double sBlend[4];
  const int t = threadIdx.x;
  const int lane = t & 63;
  const int wave = t >> 6;
  const int gw = blockIdx.x * 4 + wave;
  int lvl, row, E;
  const float *xt, *node, *edge, *init;
  int* tIdx;
  double* tCur;
  if (gw < 32768)      { lvl = 0; row = gw;          E = 2048; xt = xt0; node = node0; edge = edge0; init = init0; tIdx = tIdx0; tCur = tCur0; }
  else if (gw < 49152) { lvl = 1; row = gw - 32768;  E = 1024; xt = xt1; node = node1; edge = edge1; init = init1; tIdx = tIdx1; tCur = tCur1; }
  else                 { lvl = 2; row = gw - 49152;  E = 512;  xt = xt2; node = node2; edge = edge2; init = init2; tIdx = tIdx2; tCur = tCur2; }

  if (lane == 0) cnt[wave] = 0;

  const float* xrow = xt + (size_t)row * E;
  const int nIt = E >> 8;

  // ---- single global pass: load row into registers, lane-max + exp sum ----
  float4 vv[8];  // compile-time indexed under unroll (stays in VGPRs)
  float lmax = 0.0f;
  double s = 0.0;
#pragma unroll
  for (int j = 0; j < 8; ++j) {
    if (j < nIt) {
      const int c4 = (lane + (j << 6)) << 2;
      const float4 v = *(const float4*)(xrow + c4);
      vv[j] = v;
      s += exp2split(v.x); s += exp2split(v.y);
      s += exp2split(v.z); s += exp2split(v.w);
      lmax = fmaxf(lmax, fmaxf(fmaxf(v.x, v.y), fmaxf(v.z, v.w)));
    }
  }

  // ---- threshold: 16th distinct wave max of lane maxes ----
  float curm = lmax, T = 0.0f;
#pragma unroll 1
  for (int round = 0; round < 16; ++round) {
    float wm = curm;
#pragma unroll
    for (int d = 1; d < 64; d <<= 1) wm = fmaxf(wm, __shfl_xor(wm, d));
    T = wm;
    curm = (curm == wm) ? -1.0f : curm;
  }
  T = fmaxf(T, 1e-37f);  // degenerate-row guard (never fires on real data)

  // ---- pass 2: compact candidates x >= T from REGISTERS ----
#pragma unroll
  for (int j = 0; j < 8; ++j) {
    if (j < nIt) {
      const int c4 = (lane + (j << 6)) << 2;
      const float xs[4] = {vv[j].x, vv[j].y, vv[j].z, vv[j].w};
#pragma unroll
      for (int q = 0; q < 4; ++q) {
        if (xs[q] >= T) {
          const int sl = atomicAdd(&cnt[wave], 1);
          if (sl < 128) {
            cands[wave][sl] =
                ((unsigned long long)__float_as_uint(xs[q]) << 32) |
                (unsigned long long)(0xFFFFFFFFu - (unsigned int)(c4 + q));
          }
        }
      }
    }
  }

  // ---- select top-16 of candidates (count >= 16 guaranteed: >=16 elems >= T) ----
  const int count = min(cnt[wave], 128);
  unsigned long long c0 = (lane < count) ? cands[wave][lane] : 0ull;
  unsigned long long c1 = (64 + lane < count) ? cands[wave][64 + lane] : 0ull;
  unsigned long long mywin = 0ull;
#pragma unroll 1
  for (int round = 0; round < 16; ++round) {
    unsigned long long lm = (c0 > c1) ? c0 : c1;
#pragma unroll
    for (int d = 1; d < 64; d <<= 1) {
      const unsigned long long o = __shfl_xor(lm, d);
      lm = (o > lm) ? o : lm;
    }
    if (c0 == lm) c0 = 0ull; else if (c1 == lm) c1 = 0ull;
    if (lane == round) mywin = lm;
  }

  double sAll = s;
#pragma unroll
  for (int d = 1; d < 64; d <<= 1) sAll += __shfl_xor(sAll, d);

  // ---- f64 head recompute on lanes 0..15 (proven tail) ----
  double eh = 0.0, h32 = 0.0;
  int gc = 0;
  if (lane < 16) {
    const float x32 = __uint_as_float((unsigned int)(mywin >> 32));
    const unsigned int gcr = 0xFFFFFFFFu - (unsigned int)(mywin & 0xFFFFFFFFull);
    gc = (int)min(gcr, (unsigned int)(E - 1));  // OOB insurance (degenerate only)
    const float4* n4 = (const float4*)(node + (size_t)row * DIM);
    const float4* e4 = (const float4*)(edge + (size_t)gc * DIM);
    double acc = 0.0;
#pragma unroll
    for (int j = 0; j < 16; ++j) {
      const float4 a = n4[j], bb = e4[j];
      acc += (double)a.x * (double)bb.x + (double)a.y * (double)bb.y +
             (double)a.z * (double)bb.z + (double)a.w * (double)bb.w;
    }
    eh = exp(fmax(3.0 * acc, 0.0));
    h32 = exp2split(x32);
  }
  double ehsum = eh, h32sum = h32;
#pragma unroll
  for (int d = 1; d < 64; d <<= 1) {
    ehsum += __shfl_xor(ehsum, d);
    h32sum += __shfl_xor(h32sum, d);
  }
  const double sFix = fmax(sAll - h32sum, 0.0) + ehsum;

  double blend = 0.0;
  if (lane < 16) {
    const double cur = eh / sFix;
    tIdx[(size_t)row * 16 + lane] = gc;
    tCur[(size_t)row * 16 + lane] = cur;
    blend = 0.5 * ((double)init[(size_t)row * E + gc] + cur);
  }
#pragma unroll
  for (int d = 1; d < 64; d <<= 1) {
    const double o = __shfl_xor(blend, d);
    blend = fmax(blend, o);
  }
  if (lane == 0) sBlend[wave] = blend;
  __syncthreads();
  if (t == 0) {
    double bl = sBlend[0];
#pragma unroll
    for (int i = 1; i < 4; ++i) bl = fmax(bl, sBlend[i]);
    atomicMax(wsBlend + lvl, (unsigned long long)__double_as_longlong(bl));
  }
}

// Analytic init band parameters (verified R7).
__device__ __forceinline__ void bandParams(int i, int n, int h, int& lo, int& hi,
                                           float& vOn, float& vOff) {
  const float EINV = 0.36787944117144233f;
  const int hiRaw = i - (n - h - 17);
  if (hiRaw < 0) {
    lo = 1; hi = 0;
    vOff = 1.0f / (float)h;
    vOn = vOff;
  } else {
    lo = max(0, i - (n - h));
    hi = min(h - 1, hiRaw);
    const float m = (float)(hi - lo + 1);
    const float sum = m + ((float)h - m) * EINV;
    vOn = 1.0f / sum;
    vOff = EINV / sum;
  }
}

// Shared row-build: analytic base + 48 f64 top-k fixes into fH/fB.
__device__ __forceinline__ void buildRow(
    int r, int t, float* fH, float* fB,
    const float* init0, const float* init1, const float* init2,
    const int* tIdx0, const int* tIdx1, const int* tIdx2,
    const double* tCur0, const double* tCur1, const double* tCur2,
    const unsigned int* wsMM, const unsigned long long* wsBlend,
    float* out, bool doRetain) {
  const int r1 = r >> 1, r2 = r >> 2;
  const double mn0 = 0.5 * (double)__uint_as_float(wsMM[0]);
  const double mx0 = fmax(0.5 * (double)__uint_as_float(wsMM[1]),
                          __longlong_as_double((long long)wsBlend[0]));
  const double inv0 = 1.0 / (mx0 - mn0);
  const double mn1 = 0.5 * (double)__uint_as_float(wsMM[2]);
  const double mx1 = fmax(0.5 * (double)__uint_as_float(wsMM[3]),
                          __longlong_as_double((long long)wsBlend[1]));
  const double inv1 = 1.0 / (mx1 - mn1);
  const double mn2 = 0.5 * (double)__uint_as_float(wsMM[4]);
  const double mx2 = fmax(0.5 * (double)__uint_as_float(wsMM[5]),
                          __longlong_as_double((long long)wsBlend[2]));
  const double inv2 = 1.0 / (mx2 - mn2);

  {  // level0 cols [0,2048)
    int lo, hi; float vOn, vOff;
    bandParams(r, 32768, 2048, lo, hi, vOn, vOff);
    const float mnl = (float)mn0, il = (float)inv0;
    const float hOn = (0.5f * vOn - mnl) * il, hOff = (0.5f * vOff - mnl) * il;
#pragma unroll
    for (int p = 0; p < 2; ++p) {
      const int c = (t + (p << 8)) << 2;
      float4 h, bb;
      h.x = (c + 0 >= lo && c + 0 <= hi) ? hOn : hOff;
      h.y = (c + 1 >= lo && c + 1 <= hi) ? hOn : hOff;
      h.z = (c + 2 >= lo && c + 2 <= hi) ? hOn : hOff;
      h.w = (c + 3 >= lo && c + 3 <= hi) ? hOn : hOff;
      bb.x = (h.x > 0.5f) ? 1.0f : 0.0f; bb.y = (h.y > 0.5f) ? 1.0f : 0.0f;
      bb.z = (h.z > 0.5f) ? 1.0f : 0.0f; bb.w = (h.w > 0.5f) ? 1.0f : 0.0f;
      *(float4*)&fH[c] = h; *(float4*)&fB[c] = bb;
      if (doRetain && bb.x + bb.y + bb.z + bb.w > 0.0f) {
        if (bb.x > 0.0f) { out[OFF_R0 + c + 0] = 1.0f; out[OFF_RF + c + 0] = 1.0f; }
        if (bb.y > 0.0f) { out[OFF_R0 + c + 1] = 1.0f; out[OFF_RF + c + 1] = 1.0f; }
        if (bb.z > 0.0f) { out[OFF_R0 + c + 2] = 1.0f; out[OFF_RF + c + 2] = 1.0f; }
        if (bb.w > 0.0f) { out[OFF_R0 + c + 3] = 1.0f; out[OFF_RF + c + 3] = 1.0f; }
      }
    }
  }
  {  // level1 cols [2048,3072)
    int lo, hi; float vOn, vOff;
    bandParams(r1, 16384, 1024, lo, hi, vOn, vOff);
    const float mnl = (float)mn1, il = (float)inv1;
    const float hOn = (0.5f * vOn - mnl) * il, hOff = (0.5f * vOff - mnl) * il;
    const int cl = t << 2;
    const int c = 2048 + cl;
    float4 h, bb;
    h.x = (cl + 0 >= lo && cl + 0 <= hi) ? hOn : hOff;
    h.y = (cl + 1 >= lo && cl + 1 <= hi) ? hOn : hOff;
    h.z = (cl + 2 >= lo && cl + 2 <= hi) ? hOn : hOff;
    h.w = (cl + 3 >= lo && cl + 3 <= hi) ? hOn : hOff;
    bb.x = (h.x > 0.5f) ? 1.0f : 0.0f; bb.y = (h.y > 0.5f) ? 1.0f : 0.0f;
    bb.z = (h.z > 0.5f) ? 1.0f : 0.0f; bb.w = (h.w > 0.5f) ? 1.0f : 0.0f;
    *(float4*)&fH[c] = h; *(float4*)&fB[c] = bb;
    if (doRetain && bb.x + bb.y + bb.z + bb.w > 0.0f) {
      if (bb.x > 0.0f) { out[OFF_R1 + cl + 0] = 1.0f; out[OFF_RF + c + 0] = 1.0f; }
      if (bb.y > 0.0f) { out[OFF_R1 + cl + 1] = 1.0f; out[OFF_RF + c + 1] = 1.0f; }
      if (bb.z > 0.0f) { out[OFF_R1 + cl + 2] = 1.0f; out[OFF_RF + c + 2] = 1.0f; }
      if (bb.w > 0.0f) { out[OFF_R1 + cl + 3] = 1.0f; out[OFF_RF + c + 3] = 1.0f; }
    }
  }
  if (t < 128) {  // level2 cols [3072,3584)
    int lo, hi; float vOn, vOff;
    bandParams(r2, 8192, 512, lo, hi, vOn, vOff);
    const float mnl = (float)mn2, il = (float)inv2;
    const float hOn = (0.5f * vOn - mnl) * il, hOff = (0.5f * vOff - mnl) * il;
    const int cl = t << 2;
    const int c = 3072 + cl;
    float4 h, bb;
    h.x = (cl + 0 >= lo && cl + 0 <= hi) ? hOn : hOff;
    h.y = (cl + 1 >= lo && cl + 1 <= hi) ? hOn : hOff;
    h.z = (cl + 2 >= lo && cl + 2 <= hi) ? hOn : hOff;
    h.w = (cl + 3 >= lo && cl + 3 <= hi) ? hOn : hOff;
    bb.x = (h.x > 0.5f) ? 1.0f : 0.0f; bb.y = (h.y > 0.5f) ? 1.0f : 0.0f;
    bb.z = (h.z > 0.5f) ? 1.0f : 0.0f; bb.w = (h.w > 0.5f) ? 1.0f : 0.0f;
    *(float4*)&fH[c] = h; *(float4*)&fB[c] = bb;
    if (doRetain && bb.x + bb.y + bb.z + bb.w > 0.0f) {
      if (bb.x > 0.0f) { out[OFF_R2 + cl + 0] = 1.0f; out[OFF_RF + c + 0] = 1.0f; }
      if (bb.y > 0.0f) { out[OFF_R2 + cl + 1] = 1.0f; out[OFF_RF + c + 1] = 1.0f; }
      if (bb.z > 0.0f) { out[OFF_R2 + cl + 2] = 1.0f; out[OFF_RF + c + 2] = 1.0f; }
      if (bb.w > 0.0f) { out[OFF_R2 + cl + 3] = 1.0f; out[OFF_RF + c + 3] = 1.0f; }
    }
  }
  __syncthreads();

  if (t < 48) {
    const int lv = t >> 4, j = t & 15;
    int rowl, El, off;
    const int* ti; const double* tc; const float* in;
    size_t offR;
    double mnl, il;
    if (lv == 0)      { rowl = r;  El = 2048; off = 0;    ti = tIdx0; tc = tCur0; in = init0; offR = OFF_R0; mnl = mn0; il = inv0; }
    else if (lv == 1) { rowl = r1; El = 1024; off = 2048; ti = tIdx1; tc = tCur1; in = init1; offR = OFF_R1; mnl = mn1; il = inv1; }
    else              { rowl = r2; El = 512;  off = 3072; ti = tIdx2; tc = tCur2; in = init2; offR = OFF_R2; mnl = mn2; il = inv2; }
    const int gc = ti[(size_t)rowl * 16 + j];
    const double cur = tc[(size_t)rowl * 16 + j];
    const double adj = 0.5 * ((double)in[(size_t)rowl * El + gc] + cur);
    const double H = (adj - mnl) * il;
    const float hf = (float)H;
    const float bf = (H > 0.5) ? 1.0f : 0.0f;
    fH[off + gc] = hf;
    fB[off + gc] = bf;
    if (doRetain && bf > 0.0f) {
      out[offR + gc] = 1.0f;
      out[OFF_RF + off + gc] = 1.0f;
    }
  }
  __syncthreads();
}

// k2 (merged k2a+k2b): build row ONCE, stream fused FH/FB (1.08 GB) AND
// per-level H/B + retains (0.57 GB).
__global__ __launch_bounds__(256) void k2(
    const float* __restrict__ init0, const float* __restrict__ init1, const float* __restrict__ init2,
    const int* __restrict__ tIdx0, const int* __restrict__ tIdx1, const int* __restrict__ tIdx2,
    const double* __restrict__ tCur0, const double* __restrict__ tCur1, const double* __restrict__ tCur2,
    const unsigned int* __restrict__ wsMM, const unsigned long long* __restrict__ wsBlend,
    float* __restrict__ out) {
  __shared__ float fH[3584];
  __shared__ float fB[3584];
  const int r = blockIdx.x;
  const int t = threadIdx.x;
  const int r1 = r >> 1, r2 = r >> 2;
  buildRow(r, t, fH, fB, init0, init1, init2, tIdx0, tIdx1, tIdx2,
           tCur0, tCur1, tCur2, wsMM, wsBlend, out, true);
  const f32x4* sH = (const f32x4*)fH;
  const f32x4* sB = (const f32x4*)fB;
  // fused streams
  f32x4* FH = (f32x4*)(out + OFF_FH + (size_t)r * 3584);
  f32x4* FB = (f32x4*)(out + OFF_FB + (size_t)r * 3584);
  for (int i = t; i < 896; i += 256) {
    __builtin_nontemporal_store(sH[i], &FH[i]);
    __builtin_nontemporal_store(sB[i], &FB[i]);
  }
  // per-level streams
  f32x4* H0 = (f32x4*)(out + OFF_H0 + (size_t)r * 2048);
  f32x4* B0 = (f32x4*)(out + OFF_B0 + (size_t)r * 2048);
  for (int i = t; i < 512; i += 256) {
    __builtin_nontemporal_store(sH[i], &H0[i]);
    __builtin_nontemporal_store(sB[i], &B0[i]);
  }
  if ((r & 1) == 0) {
    f32x4* H1 = (f32x4*)(out + OFF_H1 + (size_t)r1 * 1024);
    f32x4* B1 = (f32x4*)(out + OFF_B1 + (size_t)r1 * 1024);
    __builtin_nontemporal_store(sH[512 + t], &H1[t]);
    __builtin_nontemporal_store(sB[512 + t], &B1[t]);
  }
  if ((r & 3) == 0 && t < 128) {
    f32x4* H2 = (f32x4*)(out + OFF_H2 + (size_t)r2 * 512);
    f32x4* B2 = (f32x4*)(out + OFF_B2 + (size_t)r2 * 512);
    __builtin_nontemporal_store(sH[768 + t], &H2[t]);
    __builtin_nontemporal_store(sB[768 + t], &B2[t]);
  }
}

extern "C" void kernel_launch(void* const* d_in, const int* in_sizes, int n_in,
                              void* d_out, int out_size, void* d_ws, size_t ws_size,
                              hipStream_t stream) {
  (void)in_sizes; (void)n_in; (void)out_size; (void)ws_size;
  const float* node0 = (const float*)d_in[0];
  const float* node1 = (const float*)d_in[1];
  const float* node2 = (const float*)d_in[2];
  const float* edge0 = (const float*)d_in[3];
  const float* edge1 = (const float*)d_in[4];
  const float* edge2 = (const float*)d_in[5];
  const float* init0 = (const float*)d_in[6];
  const float* init1 = (const float*)d_in[7];
  const float* init2 = (const float*)d_in[8];
  float* out = (float*)d_out;

  unsigned char* ws = (unsigned char*)d_ws;
  unsigned int* wsMM = (unsigned int*)ws;                       // 6 u32
  unsigned long long* wsBlend = (unsigned long long*)(ws + 32); // 3 u64
  int*    tIdx0 = (int*)(ws + (size_t)(1 << 20));
  int*    tIdx1 = (int*)(ws + (size_t)(3 << 20));
  int*    tIdx2 = (int*)(ws + (size_t)(4 << 20));
  double* tCur0 = (double*)(ws + (size_t)(5 << 20));
  double* tCur1 = (double*)(ws + (size_t)(9 << 20));
  double* tCur2 = (double*)(ws + (size_t)(11 << 20));
  float*  xt0   = (float*)(ws + (size_t)(16 << 20));   // 268.4 MB
  float*  xt1   = (float*)(ws + (size_t)(288 << 20));  // 67.1 MB
  float*  xt2   = (float*)(ws + (size_t)(356 << 20));  // 16.8 MB

  k_init<<<1, 256, 0, stream>>>(out, wsMM, wsBlend);
  kmm_lite<<<256, 256, 0, stream>>>(init0, init1, init2, wsMM);
  k1a<<<448, 256, 0, stream>>>(node0, node1, node2, edge0, edge1, edge2, xt0, xt1, xt2);
  k1b<<<14336, 256, 0, stream>>>(node0, node1, node2, edge0, edge1, edge2,
                                 init0, init1, init2, xt0, xt1, xt2,
                                 tIdx0, tIdx1, tIdx2, tCur0, tCur1, tCur2, wsBlend);
  k2<<<32768, 256, 0, stream>>>(init0, init1, init2, tIdx0, tIdx1, tIdx2,
                                tCur0, tCur1, tCur2, wsMM, wsBlend, out);
}